// Round 2
// baseline (256.968 us; speedup 1.0000x reference)
//
#include <hip/hip_runtime.h>
#include <hip/hip_bf16.h>
#include <stdint.h>

typedef __attribute__((ext_vector_type(8))) short s16x8;
typedef __attribute__((ext_vector_type(4))) float f32x4;

__device__ __forceinline__ unsigned short f32_bf16(float f) {
  union { float f; uint32_t u; } v; v.f = f;
  return (unsigned short)((v.u + 0x7FFFu + ((v.u >> 16) & 1u)) >> 16);
}

__device__ __forceinline__ uint32_t pack_bf16(float lo, float hi) {
  __hip_bfloat162 h = __float22bfloat162_rn(float2{lo, hi});
  union { __hip_bfloat162 h; uint32_t u; } u; u.h = h; return u.u;
}

// Exchange 4-row chunks across the four 16-lane groups to build an MFMA
// A/B fragment (k = 8*l4 + j) from C-fragment-resident data (4-chunks).
// lo*/hi* are the two source variants; lanes with bit5 set take hi*.
__device__ __forceinline__ s16x8 xchg(uint32_t lo0, uint32_t lo1,
                                      uint32_t hi0, uint32_t hi1,
                                      int srcA, int srcB, uint32_t hisel) {
  int a0 = __shfl((int)lo0, srcA), b0 = __shfl((int)hi0, srcA);
  int a1 = __shfl((int)lo1, srcA), b1 = __shfl((int)hi1, srcA);
  int a2 = __shfl((int)lo0, srcB), b2 = __shfl((int)hi0, srcB);
  int a3 = __shfl((int)lo1, srcB), b3 = __shfl((int)hi1, srcB);
  union { uint32_t u[4]; s16x8 v; } r;
  r.u[0] = hisel ? (uint32_t)b0 : (uint32_t)a0;
  r.u[1] = hisel ? (uint32_t)b1 : (uint32_t)a1;
  r.u[2] = hisel ? (uint32_t)b2 : (uint32_t)a2;
  r.u[3] = hisel ? (uint32_t)b3 : (uint32_t)a3;
  return r.v;
}

// ---------------- kernel 1: weight f32 -> bf16 ----------------
__global__ void convert_w(const float* __restrict__ wqkv,
                          const float* __restrict__ wout,
                          unsigned short* __restrict__ o) {
  int i = blockIdx.x * 256 + threadIdx.x;           // 262144 total
  if (i < 768 * 256) o[i] = f32_bf16(wqkv[i]);
  else               o[i] = f32_bf16(wout[i - 768 * 256]);
}

// ---------------- kernel 2: fused QKV + attention, all-register ----------
// block = 512 threads (8 waves), wave h handles head h. LDS = x tile only.
__global__ __launch_bounds__(512, 4) void qkv_attn(
    const float* __restrict__ x,
    const unsigned short* __restrict__ wqkv,   // [768][256] bf16
    unsigned short* __restrict__ aout) {       // [N][256] bf16
  __shared__ unsigned short xt[64 * 256];      // 32 KB, swizzled rows

  const int g    = blockIdx.x;
  const int tid  = threadIdx.x;
  const int h    = tid >> 6;
  const int lane = tid & 63;
  const int l15  = lane & 15;
  const int l4   = lane >> 4;

  // ---- stage x (64x256 f32 -> bf16, XOR swizzled rows) ----
  {
    const int row = tid >> 3;
    const int c0  = (tid & 7) * 32;
    const float* src = x + (size_t)(g * 64 + row) * 256 + c0;
    const uint32_t swz = (uint32_t)(row & 7) << 4;
#pragma unroll
    for (int c = 0; c < 32; c += 8) {
      float4 f0 = *(const float4*)(src + c);
      float4 f1 = *(const float4*)(src + c + 4);
      uint32_t p0 = pack_bf16(f0.x, f0.y);
      uint32_t p1 = pack_bf16(f0.z, f0.w);
      uint32_t p2 = pack_bf16(f1.x, f1.y);
      uint32_t p3 = pack_bf16(f1.z, f1.w);
      uint32_t byte = ((uint32_t)(row * 512 + (c0 + c) * 2)) ^ swz;
      *(uint4*)((char*)xt + byte) = make_uint4(p0, p1, p2, p3);
    }
  }
  __syncthreads();

  const uint32_t swz   = (uint32_t)(l15 & 7) << 4;
  const int      srcA  = l15 + ((lane & 16) << 1);  // l15 + 32*(l4&1)
  const int      srcB  = srcA + 16;
  const uint32_t hisel = (uint32_t)(lane & 32);

  const unsigned short* wbase = wqkv + (size_t)(h * 32 + l15) * 256 + l4 * 8;

  // ---- pass 1: qT, kT = W @ x^T (transposed production) ----
  f32x4 qT[2][4], kT[2][4];
#pragma unroll
  for (int t = 0; t < 2; ++t)
#pragma unroll
    for (int m = 0; m < 4; ++m) {
      qT[t][m] = (f32x4){0.f, 0.f, 0.f, 0.f};
      kT[t][m] = (f32x4){0.f, 0.f, 0.f, 0.f};
    }

  for (int kk = 0; kk < 8; ++kk) {
    s16x8 a[4];
#pragma unroll
    for (int m = 0; m < 4; ++m) {
      uint32_t byte = ((uint32_t)((16 * m + l15) * 512 + kk * 64 + l4 * 16)) ^ swz;
      a[m] = *(const s16x8*)((const char*)xt + byte);
    }
#pragma unroll
    for (int t = 0; t < 2; ++t) {
      const unsigned short* wp = wbase + (size_t)(16 * t) * 256 + kk * 32;
      s16x8 wq = *(const s16x8*)(wp);
      s16x8 wk = *(const s16x8*)(wp + 256 * 256);
#pragma unroll
      for (int m = 0; m < 4; ++m) {
        qT[t][m] = __builtin_amdgcn_mfma_f32_16x16x32_bf16(wq, a[m], qT[t][m], 0, 0, 0);
        kT[t][m] = __builtin_amdgcn_mfma_f32_16x16x32_bf16(wk, a[m], kT[t][m], 0, 0, 0);
      }
    }
  }

  // ---- build energy fragments in-register ----
  s16x8 kA[4], qB[4];
#pragma unroll
  for (int m = 0; m < 4; ++m) {
    uint32_t q00 = pack_bf16(qT[0][m][0], qT[0][m][1]);
    uint32_t q01 = pack_bf16(qT[0][m][2], qT[0][m][3]);
    uint32_t q10 = pack_bf16(qT[1][m][0], qT[1][m][1]);
    uint32_t q11 = pack_bf16(qT[1][m][2], qT[1][m][3]);
    qB[m] = xchg(q00, q01, q10, q11, srcA, srcB, hisel);
    uint32_t k00 = pack_bf16(kT[0][m][0], kT[0][m][1]);
    uint32_t k01 = pack_bf16(kT[0][m][2], kT[0][m][3]);
    uint32_t k10 = pack_bf16(kT[1][m][0], kT[1][m][1]);
    uint32_t k11 = pack_bf16(kT[1][m][2], kT[1][m][3]);
    kA[m] = xchg(k00, k01, k10, k11, srcA, srcB, hisel);
  }

  // ---- energy^T[ktok][qtok] = K Q^T : P-rows land lane-local ----
  f32x4 e[4][4];
#pragma unroll
  for (int m = 0; m < 4; ++m)
#pragma unroll
    for (int n = 0; n < 4; ++n) {
      e[m][n] = (f32x4){0.f, 0.f, 0.f, 0.f};
      e[m][n] = __builtin_amdgcn_mfma_f32_16x16x32_bf16(kA[m], qB[n], e[m][n], 0, 0, 0);
    }

  // ---- softmax over ktok (regs + 2 shfl), pack P to bf16 ----
  uint32_t pkP[4][4][2];
#pragma unroll
  for (int n = 0; n < 4; ++n) {
    float mx = e[0][n][0];
#pragma unroll
    for (int m = 0; m < 4; ++m)
#pragma unroll
      for (int r = 0; r < 4; ++r) mx = fmaxf(mx, e[m][n][r]);
    mx = fmaxf(mx, __shfl_xor(mx, 16));
    mx = fmaxf(mx, __shfl_xor(mx, 32));
    float p[4][4];
    float sum = 0.f;
#pragma unroll
    for (int m = 0; m < 4; ++m)
#pragma unroll
      for (int r = 0; r < 4; ++r) {
        float t = __expf((e[m][n][r] - mx) * 0.0625f);  // scale 1/sqrt(256)
        p[m][r] = t;
        sum += t;
      }
    sum += __shfl_xor(sum, 16);
    sum += __shfl_xor(sum, 32);
    float rs = 1.0f / sum;
#pragma unroll
    for (int m = 0; m < 4; ++m) {
      pkP[n][m][0] = pack_bf16(p[m][0] * rs, p[m][1] * rs);
      pkP[n][m][1] = pack_bf16(p[m][2] * rs, p[m][3] * rs);
    }
  }

  // ---- pass 2: v = x @ Wv^T (normal production) ----
  f32x4 vv[4][2];
#pragma unroll
  for (int m = 0; m < 4; ++m) {
    vv[m][0] = (f32x4){0.f, 0.f, 0.f, 0.f};
    vv[m][1] = (f32x4){0.f, 0.f, 0.f, 0.f};
  }
  for (int kk = 0; kk < 8; ++kk) {
    s16x8 a[4];
#pragma unroll
    for (int m = 0; m < 4; ++m) {
      uint32_t byte = ((uint32_t)((16 * m + l15) * 512 + kk * 64 + l4 * 16)) ^ swz;
      a[m] = *(const s16x8*)((const char*)xt + byte);
    }
    const unsigned short* wp = wbase + (size_t)512 * 256 + kk * 32;
    s16x8 wv0 = *(const s16x8*)(wp);
    s16x8 wv1 = *(const s16x8*)(wp + 16 * 256);
#pragma unroll
    for (int m = 0; m < 4; ++m) {
      vv[m][0] = __builtin_amdgcn_mfma_f32_16x16x32_bf16(a[m], wv0, vv[m][0], 0, 0, 0);
      vv[m][1] = __builtin_amdgcn_mfma_f32_16x16x32_bf16(a[m], wv1, vv[m][1], 0, 0, 0);
    }
  }
  uint32_t pkV[2][4][2];
#pragma unroll
  for (int t = 0; t < 2; ++t)
#pragma unroll
    for (int m = 0; m < 4; ++m) {
      pkV[t][m][0] = pack_bf16(vv[m][t][0], vv[m][t][1]);
      pkV[t][m][1] = pack_bf16(vv[m][t][2], vv[m][t][3]);
    }

  // ---- out = P @ V (K=64 in 2 steps), frags via exchange ----
  f32x4 o[4][2];
#pragma unroll
  for (int nb = 0; nb < 4; ++nb) {
    o[nb][0] = (f32x4){0.f, 0.f, 0.f, 0.f};
    o[nb][1] = (f32x4){0.f, 0.f, 0.f, 0.f};
  }
#pragma unroll
  for (int kk2 = 0; kk2 < 2; ++kk2) {
    s16x8 vB[2];
#pragma unroll
    for (int t = 0; t < 2; ++t)
      vB[t] = xchg(pkV[t][2 * kk2][0], pkV[t][2 * kk2][1],
                   pkV[t][2 * kk2 + 1][0], pkV[t][2 * kk2 + 1][1], srcA, srcB, hisel);
#pragma unroll
    for (int nb = 0; nb < 4; ++nb) {
      s16x8 pA = xchg(pkP[nb][2 * kk2][0], pkP[nb][2 * kk2][1],
                      pkP[nb][2 * kk2 + 1][0], pkP[nb][2 * kk2 + 1][1], srcA, srcB, hisel);
      o[nb][0] = __builtin_amdgcn_mfma_f32_16x16x32_bf16(pA, vB[0], o[nb][0], 0, 0, 0);
      o[nb][1] = __builtin_amdgcn_mfma_f32_16x16x32_bf16(pA, vB[1], o[nb][1], 0, 0, 0);
    }
  }

  // ---- store attn output (bf16) ----
  unsigned short* dst = aout + (size_t)g * 64 * 256 + h * 32;
#pragma unroll
  for (int nb = 0; nb < 4; ++nb)
#pragma unroll
    for (int t = 0; t < 2; ++t)
#pragma unroll
      for (int r = 0; r < 4; ++r)
        dst[(size_t)(16 * nb + 4 * l4 + r) * 256 + 16 * t + l15] = f32_bf16(o[nb][t][r]);
}

// ---------------- kernel 3: out = attn @ w_out^T + b ----------------
// 128x128 tile, 4 waves (2x2), BK=64, swizzled reg-staged LDS
__global__ __launch_bounds__(256) void proj(
    const unsigned short* __restrict__ A,    // [131072][256] bf16
    const unsigned short* __restrict__ Bw,   // [256][256] bf16
    const float* __restrict__ bias,
    float* __restrict__ out) {
  __shared__ unsigned short As[128 * 64];
  __shared__ unsigned short Bs[128 * 64];
  const int bm = blockIdx.x, bn = blockIdx.y;
  const int tid = threadIdx.x;
  const int w = tid >> 6, lane = tid & 63;
  const int l15 = lane & 15, l4 = lane >> 4;
  const int wr = w >> 1, wc = w & 1;

  f32x4 acc[4][4];
#pragma unroll
  for (int mi = 0; mi < 4; ++mi)
#pragma unroll
    for (int ni = 0; ni < 4; ++ni) acc[mi][ni] = (f32x4){0.f, 0.f, 0.f, 0.f};

  const int srow = tid >> 1;
  const int sc0  = (tid & 1) * 32;
  const unsigned short* ga = A  + (size_t)(bm * 128 + srow) * 256 + sc0;
  const unsigned short* gb = Bw + (size_t)(bn * 128 + srow) * 256 + sc0;

  for (int kk = 0; kk < 4; ++kk) {
#pragma unroll
    for (int c = 0; c < 32; c += 8) {
      uint4 va = *(const uint4*)(ga + kk * 64 + c);
      uint4 vb = *(const uint4*)(gb + kk * 64 + c);
      uint32_t byte = (uint32_t)(srow * 128 + (sc0 + c) * 2) ^ ((srow & 7) << 4);
      *(uint4*)((char*)As + byte) = va;
      *(uint4*)((char*)Bs + byte) = vb;
    }
    __syncthreads();
#pragma unroll
    for (int k2 = 0; k2 < 2; ++k2) {
      s16x8 af[4], bf[4];
#pragma unroll
      for (int mi = 0; mi < 4; ++mi) {
        int row = wr * 64 + 16 * mi + l15;
        uint32_t byte = (uint32_t)(row * 128 + k2 * 64 + l4 * 16) ^ ((row & 7) << 4);
        af[mi] = *(const s16x8*)((const char*)As + byte);
      }
#pragma unroll
      for (int ni = 0; ni < 4; ++ni) {
        int row = wc * 64 + 16 * ni + l15;
        uint32_t byte = (uint32_t)(row * 128 + k2 * 64 + l4 * 16) ^ ((row & 7) << 4);
        bf[ni] = *(const s16x8*)((const char*)Bs + byte);
      }
#pragma unroll
      for (int mi = 0; mi < 4; ++mi)
#pragma unroll
        for (int ni = 0; ni < 4; ++ni)
          acc[mi][ni] = __builtin_amdgcn_mfma_f32_16x16x32_bf16(af[mi], bf[ni], acc[mi][ni], 0, 0, 0);
    }
    __syncthreads();
  }

#pragma unroll
  for (int mi = 0; mi < 4; ++mi)
#pragma unroll
    for (int ni = 0; ni < 4; ++ni) {
      int col = bn * 128 + wc * 64 + 16 * ni + l15;
      float b = bias[col];
#pragma unroll
      for (int r = 0; r < 4; ++r) {
        int row = bm * 128 + wr * 64 + 16 * mi + l4 * 4 + r;
        out[(size_t)row * 256 + col] = acc[mi][ni][r] + b;
      }
    }
}

extern "C" void kernel_launch(void* const* d_in, const int* in_sizes, int n_in,
                              void* d_out, int out_size, void* d_ws, size_t ws_size,
                              hipStream_t stream) {
  const float* x    = (const float*)d_in[0];
  const float* wqkv = (const float*)d_in[1];
  const float* wout = (const float*)d_in[2];
  const float* bout = (const float*)d_in[3];
  float* out = (float*)d_out;

  unsigned short* wq_bf = (unsigned short*)d_ws;          // 768*256 bf16
  unsigned short* wo_bf = wq_bf + 768 * 256;              // 256*256 bf16
  unsigned short* aout  = wo_bf + 256 * 256;              // 131072*256 bf16

  convert_w<<<1024, 256, 0, stream>>>(wqkv, wout, wq_bf);
  qkv_attn<<<2048, 512, 0, stream>>>(x, wq_bf, aout);
  proj<<<dim3(1024, 2), 256, 0, stream>>>(aout, wo_bf, bout, out);
}

// Round 3
// 209.144 us; speedup vs baseline: 1.2287x; 1.2287x over previous
//
#include <hip/hip_runtime.h>
#include <hip/hip_bf16.h>
#include <stdint.h>

typedef __attribute__((ext_vector_type(8))) short s16x8;
typedef __attribute__((ext_vector_type(4))) float f32x4;

__device__ __forceinline__ unsigned short f32_bf16(float f) {
  union { float f; uint32_t u; } v; v.f = f;
  return (unsigned short)((v.u + 0x7FFFu + ((v.u >> 16) & 1u)) >> 16);
}

__device__ __forceinline__ uint32_t pack_bf16(float lo, float hi) {
  __hip_bfloat162 h = __float22bfloat162_rn(float2{lo, hi});
  union { __hip_bfloat162 h; uint32_t u; } u; u.h = h; return u.u;
}

// Exchange 4-row chunks across the four 16-lane groups to build an MFMA
// A/B fragment (k = 8*l4 + j) from C-fragment-resident data (4-chunks).
__device__ __forceinline__ s16x8 xchg(uint32_t lo0, uint32_t lo1,
                                      uint32_t hi0, uint32_t hi1,
                                      int srcA, int srcB, uint32_t hisel) {
  int a0 = __shfl((int)lo0, srcA), b0 = __shfl((int)hi0, srcA);
  int a1 = __shfl((int)lo1, srcA), b1 = __shfl((int)hi1, srcA);
  int a2 = __shfl((int)lo0, srcB), b2 = __shfl((int)hi0, srcB);
  int a3 = __shfl((int)lo1, srcB), b3 = __shfl((int)hi1, srcB);
  union { uint32_t u[4]; s16x8 v; } r;
  r.u[0] = hisel ? (uint32_t)b0 : (uint32_t)a0;
  r.u[1] = hisel ? (uint32_t)b1 : (uint32_t)a1;
  r.u[2] = hisel ? (uint32_t)b2 : (uint32_t)a2;
  r.u[3] = hisel ? (uint32_t)b3 : (uint32_t)a3;
  return r.v;
}

// ---------------- kernel 1: weights f32 -> bf16 ----------------
__global__ void convert_w(const float* __restrict__ wqkv,
                          const float* __restrict__ wout,
                          unsigned short* __restrict__ o) {
  int i = blockIdx.x * 256 + threadIdx.x;           // 262144 total
  if (i < 768 * 256) o[i] = f32_bf16(wqkv[i]);
  else               o[i] = f32_bf16(wout[i - 768 * 256]);
}

// ------- kernel 2: fused QKV + attention + out-projection, per group -----
// block = 512 threads (8 waves), wave h handles head h. LDS = 32KB x-tile,
// reused for the attention-output tile before the fused projection.
__global__ __launch_bounds__(512, 2) void mha_fused(
    const float* __restrict__ x,
    const unsigned short* __restrict__ wqkv,   // [768][256] bf16
    const unsigned short* __restrict__ wout,   // [256][256] bf16
    const float* __restrict__ bias,            // [256] f32
    float* __restrict__ out) {                 // [N][256] f32
  __shared__ unsigned short xt[64 * 256];      // 32 KB, swizzled rows

  const int g    = blockIdx.x;
  const int tid  = threadIdx.x;
  const int h    = tid >> 6;
  const int lane = tid & 63;
  const int l15  = lane & 15;
  const int l4   = lane >> 4;

  // ---- stage x (64x256 f32 -> bf16, XOR swizzled rows) ----
  {
    const int row = tid >> 3;
    const int c0  = (tid & 7) * 32;
    const float* src = x + (size_t)(g * 64 + row) * 256 + c0;
    const uint32_t swz = (uint32_t)(row & 7) << 4;
#pragma unroll
    for (int c = 0; c < 32; c += 8) {
      float4 f0 = *(const float4*)(src + c);
      float4 f1 = *(const float4*)(src + c + 4);
      uint32_t p0 = pack_bf16(f0.x, f0.y);
      uint32_t p1 = pack_bf16(f0.z, f0.w);
      uint32_t p2 = pack_bf16(f1.x, f1.y);
      uint32_t p3 = pack_bf16(f1.z, f1.w);
      uint32_t byte = ((uint32_t)(row * 512 + (c0 + c) * 2)) ^ swz;
      *(uint4*)((char*)xt + byte) = make_uint4(p0, p1, p2, p3);
    }
  }
  __syncthreads();

  const uint32_t swz   = (uint32_t)(l15 & 7) << 4;
  const int      srcA  = l15 + ((lane & 16) << 1);  // l15 + 32*(l4&1)
  const int      srcB  = srcA + 16;
  const uint32_t hisel = (uint32_t)(lane & 32);

  const unsigned short* wbase = wqkv + (size_t)(h * 32 + l15) * 256 + l4 * 8;

  // ---- pass 1: qT, kT = W @ x^T (transposed production) ----
  f32x4 qT[2][4], kT[2][4];
#pragma unroll
  for (int t = 0; t < 2; ++t)
#pragma unroll
    for (int m = 0; m < 4; ++m) {
      qT[t][m] = (f32x4){0.f, 0.f, 0.f, 0.f};
      kT[t][m] = (f32x4){0.f, 0.f, 0.f, 0.f};
    }

  for (int kk = 0; kk < 8; ++kk) {
    s16x8 a[4];
#pragma unroll
    for (int m = 0; m < 4; ++m) {
      uint32_t byte = ((uint32_t)((16 * m + l15) * 512 + kk * 64 + l4 * 16)) ^ swz;
      a[m] = *(const s16x8*)((const char*)xt + byte);
    }
#pragma unroll
    for (int t = 0; t < 2; ++t) {
      const unsigned short* wp = wbase + (size_t)(16 * t) * 256 + kk * 32;
      s16x8 wq = *(const s16x8*)(wp);
      s16x8 wk = *(const s16x8*)(wp + 256 * 256);
#pragma unroll
      for (int m = 0; m < 4; ++m) {
        qT[t][m] = __builtin_amdgcn_mfma_f32_16x16x32_bf16(wq, a[m], qT[t][m], 0, 0, 0);
        kT[t][m] = __builtin_amdgcn_mfma_f32_16x16x32_bf16(wk, a[m], kT[t][m], 0, 0, 0);
      }
    }
  }

  // ---- build energy fragments in-register ----
  s16x8 kA[4], qB[4];
#pragma unroll
  for (int m = 0; m < 4; ++m) {
    uint32_t q00 = pack_bf16(qT[0][m][0], qT[0][m][1]);
    uint32_t q01 = pack_bf16(qT[0][m][2], qT[0][m][3]);
    uint32_t q10 = pack_bf16(qT[1][m][0], qT[1][m][1]);
    uint32_t q11 = pack_bf16(qT[1][m][2], qT[1][m][3]);
    qB[m] = xchg(q00, q01, q10, q11, srcA, srcB, hisel);
    uint32_t k00 = pack_bf16(kT[0][m][0], kT[0][m][1]);
    uint32_t k01 = pack_bf16(kT[0][m][2], kT[0][m][3]);
    uint32_t k10 = pack_bf16(kT[1][m][0], kT[1][m][1]);
    uint32_t k11 = pack_bf16(kT[1][m][2], kT[1][m][3]);
    kA[m] = xchg(k00, k01, k10, k11, srcA, srcB, hisel);
  }

  // ---- energy^T + softmax per q-block (keeps only 4 e-accs live) ----
  uint32_t pkP[4][4][2];
#pragma unroll
  for (int n = 0; n < 4; ++n) {
    f32x4 en[4];
#pragma unroll
    for (int m = 0; m < 4; ++m) {
      en[m] = (f32x4){0.f, 0.f, 0.f, 0.f};
      en[m] = __builtin_amdgcn_mfma_f32_16x16x32_bf16(kA[m], qB[n], en[m], 0, 0, 0);
    }
    float mx = en[0][0];
#pragma unroll
    for (int m = 0; m < 4; ++m)
#pragma unroll
      for (int r = 0; r < 4; ++r) mx = fmaxf(mx, en[m][r]);
    mx = fmaxf(mx, __shfl_xor(mx, 16));
    mx = fmaxf(mx, __shfl_xor(mx, 32));
    float p[4][4];
    float sum = 0.f;
#pragma unroll
    for (int m = 0; m < 4; ++m)
#pragma unroll
      for (int r = 0; r < 4; ++r) {
        float t = __expf((en[m][r] - mx) * 0.0625f);  // scale 1/sqrt(256)
        p[m][r] = t;
        sum += t;
      }
    sum += __shfl_xor(sum, 16);
    sum += __shfl_xor(sum, 32);
    float rs = 1.0f / sum;
#pragma unroll
    for (int m = 0; m < 4; ++m) {
      pkP[n][m][0] = pack_bf16(p[m][0] * rs, p[m][1] * rs);
      pkP[n][m][1] = pack_bf16(p[m][2] * rs, p[m][3] * rs);
    }
  }

  // ---- pass 2: v = x @ Wv^T (normal production) ----
  f32x4 vv[4][2];
#pragma unroll
  for (int m = 0; m < 4; ++m) {
    vv[m][0] = (f32x4){0.f, 0.f, 0.f, 0.f};
    vv[m][1] = (f32x4){0.f, 0.f, 0.f, 0.f};
  }
  for (int kk = 0; kk < 8; ++kk) {
    s16x8 a[4];
#pragma unroll
    for (int m = 0; m < 4; ++m) {
      uint32_t byte = ((uint32_t)((16 * m + l15) * 512 + kk * 64 + l4 * 16)) ^ swz;
      a[m] = *(const s16x8*)((const char*)xt + byte);
    }
    const unsigned short* wp = wbase + (size_t)512 * 256 + kk * 32;
    s16x8 wv0 = *(const s16x8*)(wp);
    s16x8 wv1 = *(const s16x8*)(wp + 16 * 256);
#pragma unroll
    for (int m = 0; m < 4; ++m) {
      vv[m][0] = __builtin_amdgcn_mfma_f32_16x16x32_bf16(a[m], wv0, vv[m][0], 0, 0, 0);
      vv[m][1] = __builtin_amdgcn_mfma_f32_16x16x32_bf16(a[m], wv1, vv[m][1], 0, 0, 0);
    }
  }
  uint32_t pkV[2][4][2];
#pragma unroll
  for (int t = 0; t < 2; ++t)
#pragma unroll
    for (int m = 0; m < 4; ++m) {
      pkV[t][m][0] = pack_bf16(vv[m][t][0], vv[m][t][1]);
      pkV[t][m][1] = pack_bf16(vv[m][t][2], vv[m][t][3]);
    }

  // ---- attn = P @ V (K=64 in 2 steps), frags via exchange ----
  f32x4 o[4][2];
#pragma unroll
  for (int nb = 0; nb < 4; ++nb) {
    o[nb][0] = (f32x4){0.f, 0.f, 0.f, 0.f};
    o[nb][1] = (f32x4){0.f, 0.f, 0.f, 0.f};
  }
#pragma unroll
  for (int kk2 = 0; kk2 < 2; ++kk2) {
    s16x8 vB[2];
#pragma unroll
    for (int t = 0; t < 2; ++t)
      vB[t] = xchg(pkV[t][2 * kk2][0], pkV[t][2 * kk2][1],
                   pkV[t][2 * kk2 + 1][0], pkV[t][2 * kk2 + 1][1], srcA, srcB, hisel);
#pragma unroll
    for (int nb = 0; nb < 4; ++nb) {
      s16x8 pA = xchg(pkP[nb][2 * kk2][0], pkP[nb][2 * kk2][1],
                      pkP[nb][2 * kk2 + 1][0], pkP[nb][2 * kk2 + 1][1], srcA, srcB, hisel);
      o[nb][0] = __builtin_amdgcn_mfma_f32_16x16x32_bf16(pA, vB[0], o[nb][0], 0, 0, 0);
      o[nb][1] = __builtin_amdgcn_mfma_f32_16x16x32_bf16(pA, vB[1], o[nb][1], 0, 0, 0);
    }
  }

  // ---- stage attn tile back into xt (all waves done reading x) ----
  __syncthreads();
#pragma unroll
  for (int nb = 0; nb < 4; ++nb)
#pragma unroll
    for (int t = 0; t < 2; ++t)
#pragma unroll
      for (int r = 0; r < 4; ++r) {
        int row = 16 * nb + 4 * l4 + r;
        int col = h * 32 + 16 * t + l15;
        uint32_t byte = ((uint32_t)(row * 512 + col * 2)) ^ ((uint32_t)(row & 7) << 4);
        *(unsigned short*)((char*)xt + byte) = f32_bf16(o[nb][t][r]);
      }
  __syncthreads();

  // ---- fused out-projection: out[:, h*32..h*32+31] = attn @ wout^T + b ----
  f32x4 acc[4][2];
#pragma unroll
  for (int m = 0; m < 4; ++m) {
    acc[m][0] = (f32x4){0.f, 0.f, 0.f, 0.f};
    acc[m][1] = (f32x4){0.f, 0.f, 0.f, 0.f};
  }
  const unsigned short* wobase = wout + (size_t)(h * 32 + l15) * 256 + l4 * 8;
  for (int kk = 0; kk < 8; ++kk) {
    s16x8 a[4];
#pragma unroll
    for (int m = 0; m < 4; ++m) {
      uint32_t byte = ((uint32_t)((16 * m + l15) * 512 + kk * 64 + l4 * 16)) ^ swz;
      a[m] = *(const s16x8*)((const char*)xt + byte);
    }
    s16x8 wo0 = *(const s16x8*)(wobase + kk * 32);
    s16x8 wo1 = *(const s16x8*)(wobase + (size_t)16 * 256 + kk * 32);
#pragma unroll
    for (int m = 0; m < 4; ++m) {
      acc[m][0] = __builtin_amdgcn_mfma_f32_16x16x32_bf16(a[m], wo0, acc[m][0], 0, 0, 0);
      acc[m][1] = __builtin_amdgcn_mfma_f32_16x16x32_bf16(a[m], wo1, acc[m][1], 0, 0, 0);
    }
  }

  const float b0 = bias[h * 32 + l15];
  const float b1 = bias[h * 32 + 16 + l15];
  float* dst = out + (size_t)g * 64 * 256 + h * 32;
#pragma unroll
  for (int m = 0; m < 4; ++m)
#pragma unroll
    for (int r = 0; r < 4; ++r) {
      int tok = 16 * m + 4 * l4 + r;
      dst[(size_t)tok * 256 + l15]      = acc[m][0][r] + b0;
      dst[(size_t)tok * 256 + 16 + l15] = acc[m][1][r] + b1;
    }
}

extern "C" void kernel_launch(void* const* d_in, const int* in_sizes, int n_in,
                              void* d_out, int out_size, void* d_ws, size_t ws_size,
                              hipStream_t stream) {
  const float* x    = (const float*)d_in[0];
  const float* wqkv = (const float*)d_in[1];
  const float* wout = (const float*)d_in[2];
  const float* bout = (const float*)d_in[3];
  float* out = (float*)d_out;

  unsigned short* wq_bf = (unsigned short*)d_ws;          // 768*256 bf16
  unsigned short* wo_bf = wq_bf + 768 * 256;              // 256*256 bf16

  convert_w<<<1024, 256, 0, stream>>>(wqkv, wout, wq_bf);
  mha_fused<<<2048, 512, 0, stream>>>(x, wq_bf, wo_bf, bout, out);
}